// Round 1
// baseline (328.070 us; speedup 1.0000x reference)
//
#include <hip/hip_runtime.h>

#define NODES 100000
#define IN_F 128
#define OUT_F 32

// ---------------------------------------------------------------------------
// Kernel 1: z = x @ W + b   (100000 x 128) * (128 x 32)
// Block: 256 threads, 64 rows of x per block.
// LDS: x tile 64*128*4 = 32 KB, W 128*32*4 = 16 KB -> 48 KB -> 3 blocks/CU.
// Thread t: col = t&31, rowgroup = t>>5; computes 8 rows (rg, rg+8, ..., rg+56).
// LDS access pattern: x reads broadcast within 32-lane group (conflict-free),
// W reads stride-1 across 32 lanes (conflict-free).
// ---------------------------------------------------------------------------
__global__ __launch_bounds__(256) void zgemm_kernel(
    const float* __restrict__ x, const float* __restrict__ W,
    const float* __restrict__ b, float* __restrict__ z, int n_nodes)
{
    __shared__ float xs[64 * IN_F];      // 32 KB
    __shared__ float Ws[IN_F * OUT_F];   // 16 KB
    __shared__ float bs[OUT_F];

    const int t = threadIdx.x;
    const int row0 = blockIdx.x * 64;
    const int rows = min(64, n_nodes - row0);

    // Stage W (4096 floats = 1024 float4; 4 per thread) — coalesced.
    {
        const float4* Wv = (const float4*)W;
        float4* Wsv = (float4*)Ws;
        #pragma unroll
        for (int i = 0; i < 4; ++i)
            Wsv[t + i * 256] = Wv[t + i * 256];
        if (t < OUT_F) bs[t] = b[t];
    }
    // Stage x tile (rows*128 floats = rows*32 float4) — coalesced.
    {
        const float4* xv = (const float4*)(x + (size_t)row0 * IN_F);
        float4* xsv = (float4*)xs;
        const int nv = rows * (IN_F / 4);
        for (int i = t; i < nv; i += 256)
            xsv[i] = xv[i];
    }
    __syncthreads();

    const int col = t & 31;
    const int rg  = t >> 5;   // 0..7

    float acc[8];
    #pragma unroll
    for (int i = 0; i < 8; ++i) acc[i] = 0.f;

    for (int k = 0; k < IN_F; ++k) {
        const float wv = Ws[k * OUT_F + col];
        #pragma unroll
        for (int i = 0; i < 8; ++i)
            acc[i] += xs[(rg + i * 8) * IN_F + k] * wv;
    }

    const float bb = bs[col];
    #pragma unroll
    for (int i = 0; i < 8; ++i) {
        const int r = rg + i * 8;
        if (r < rows)
            z[(size_t)(row0 + r) * OUT_F + col] = acc[i] + bb;
    }
}

// ---------------------------------------------------------------------------
// Kernel 2: out[e][:] = vals[e] * (z[rows[e]][:] + z[cols[e]][:])
// 8 lanes per edge, float4 per lane -> one wave covers 8 consecutive edges,
// writing 1024 contiguous bytes (perfectly coalesced). z gathers are
// contiguous 128 B segments (z is only 12.8 MB -> L2/L3 resident).
// ---------------------------------------------------------------------------
__global__ __launch_bounds__(256) void edge_kernel(
    const int* __restrict__ erows, const int* __restrict__ ecols,
    const float* __restrict__ evals, const float* __restrict__ z,
    float* __restrict__ out, int n_edges)
{
    const size_t g = (size_t)blockIdx.x * 256 + threadIdx.x;
    const size_t e = g >> 3;
    if (e >= (size_t)n_edges) return;
    const int joff = (int)(g & 7) << 2;   // 0,4,8,...,28

    const int r = erows[e];
    const int c = ecols[e];
    const float w = evals[e];

    const float4 zr = *(const float4*)(z + (size_t)r * OUT_F + joff);
    const float4 zc = *(const float4*)(z + (size_t)c * OUT_F + joff);

    float4 o;
    o.x = w * (zr.x + zc.x);
    o.y = w * (zr.y + zc.y);
    o.z = w * (zr.z + zc.z);
    o.w = w * (zr.w + zc.w);

    *(float4*)(out + e * OUT_F + joff) = o;
}

extern "C" void kernel_launch(void* const* d_in, const int* in_sizes, int n_in,
                              void* d_out, int out_size, void* d_ws, size_t ws_size,
                              hipStream_t stream)
{
    const float* x  = (const float*)d_in[0];   // (100000, 128)
    const float* W  = (const float*)d_in[1];   // (128, 32)
    const float* b  = (const float*)d_in[2];   // (32,)
    const int* erow = (const int*)d_in[3];     // (E,) int32
    const int* ecol = (const int*)d_in[4];     // (E,) int32
    const float* ev = (const float*)d_in[5];   // (E,)

    const int n_nodes = in_sizes[0] / IN_F;
    const int n_edges = in_sizes[3];

    float* z   = (float*)d_ws;                 // n_nodes*32*4 = 12.8 MB scratch
    float* out = (float*)d_out;                // (E, 32)

    const int gemm_blocks = (n_nodes + 63) / 64;
    zgemm_kernel<<<gemm_blocks, 256, 0, stream>>>(x, W, b, z, n_nodes);

    const size_t total_thr = (size_t)n_edges * 8;
    const int edge_blocks = (int)((total_thr + 255) / 256);
    edge_kernel<<<edge_blocks, 256, 0, stream>>>(erow, ecol, ev, z, out, n_edges);
}